// Round 8
// baseline (114.282 us; speedup 1.0000x reference)
//
#include <hip/hip_runtime.h>
#include <hip/hip_bf16.h>
#include <math.h>

#define BB 256
#define FF 1024
#define GG 512
#define SS 512
#define EE 256
#define PP 8
#define TT 256

typedef __attribute__((ext_vector_type(8))) short bs8;     // 8 bf16
typedef __attribute__((ext_vector_type(4))) float f32x4;

__device__ __forceinline__ float sigmoidf_(float x) { return 1.0f / (1.0f + expf(-x)); }

__device__ __forceinline__ short f2bf(float f) {
    union { float f; unsigned u; } v; v.f = f;
    unsigned r = v.u + 0x7FFFu + ((v.u >> 16) & 1u);   // RNE
    return (short)(r >> 16);
}

union BPack { bs8 s; __hip_bfloat162 h[4]; };

__device__ __forceinline__ bs8 ld8cvt(const float* p) {
    float4 a = *(const float4*)p, b = *(const float4*)(p + 4);
    BPack u;
    u.h[0] = __float22bfloat162_rn({a.x, a.y});
    u.h[1] = __float22bfloat162_rn({a.z, a.w});
    u.h[2] = __float22bfloat162_rn({b.x, b.y});
    u.h[3] = __float22bfloat162_rn({b.z, b.w});
    return u.s;
}
__device__ __forceinline__ void ld8split(const float* p, bs8& ho, bs8& lo) {
    float4 a = *(const float4*)p, b = *(const float4*)(p + 4);
    float v[8] = {a.x, a.y, a.z, a.w, b.x, b.y, b.z, b.w};
    BPack uh, ul;
#pragma unroll
    for (int j = 0; j < 4; ++j) {
        __hip_bfloat162 h2 = __float22bfloat162_rn({v[2*j], v[2*j+1]});
        uh.h[j] = h2;
        float r0 = v[2*j]   - __low2float(h2);
        float r1 = v[2*j+1] - __high2float(h2);
        ul.h[j] = __float22bfloat162_rn({r0, r1});
    }
    ho = uh.s; lo = ul.s;
}

// ---------------------------------------------------------------------------
// W slab layout (elements)
// ---------------------------------------------------------------------------
#define OWG_IH 0L
#define OWG_HH 2359296L
#define OWP_IH 3145728L
#define OWP_HH 5505024L
#define OWE_IH 6291456L
#define OWE_HH 6684672L
#define WTOT   6881280L

// block-range boundaries for k_mega
#define MB1 3360     // W slab conv          (3360 blocks)
#define MB2 3616     // attn_W hi/lo split   (256)
#define MB3 3744     // feature -> xg/fhi/flo(128)
#define MB4 3808     // h_g -> hg_bf         (64)
#define MB5 3840     // emotion0 -> emo_bf   (32)
#define MBE 4096     // gather               (256)

__global__ __launch_bounds__(256) void k_mega(
        const float* __restrict__ Wg_ih, const float* __restrict__ Wg_hh,
        const float* __restrict__ Wp_ih, const float* __restrict__ Wp_hh,
        const float* __restrict__ We_ih, const float* __restrict__ We_hh,
        const float* __restrict__ attn_W, const float* __restrict__ feature_,
        const float* __restrict__ h_g, const float* __restrict__ emotion0,
        const float* __restrict__ mask, const float* __restrict__ sp0,
        short* __restrict__ Wbf, short* __restrict__ awhi, short* __restrict__ awlo,
        short* __restrict__ xg, short* __restrict__ fhi, short* __restrict__ flo,
        short* __restrict__ hg_bf, short* __restrict__ emo_bf, short* __restrict__ sel0_bf,
        float* __restrict__ sel0, int* __restrict__ spk) {
    int blk = blockIdx.x, tid = threadIdx.x;
    if (blk < MB1) {
        long i = (long)blk * 2048 + tid * 8;
        const float* src; long base;
        if      (i < OWG_HH) { src = Wg_ih; base = OWG_IH; }
        else if (i < OWP_IH) { src = Wg_hh; base = OWG_HH; }
        else if (i < OWP_HH) { src = Wp_ih; base = OWP_IH; }
        else if (i < OWE_IH) { src = Wp_hh; base = OWP_HH; }
        else if (i < OWE_HH) { src = We_ih; base = OWE_IH; }
        else                 { src = We_hh; base = OWE_HH; }
        *(bs8*)(Wbf + i) = ld8cvt(src + (i - base));
    } else if (blk < MB2) {
        long i = (long)(blk - MB1) * 2048 + tid * 8;
        bs8 h, l;
        ld8split(attn_W + i, h, l);
        *(bs8*)(awhi + i) = h;
        *(bs8*)(awlo + i) = l;
    } else if (blk < MB3) {
        long i = (long)(blk - MB2) * 2048 + tid * 8;
        bs8 h, l;
        ld8split(feature_ + i, h, l);
        *(bs8*)(fhi + i) = h;
        *(bs8*)(flo + i) = l;
        long b = i >> 10, c = i & 1023;
        *(bs8*)(xg + b * 1536 + c) = h;
    } else if (blk < MB4) {
        long i = (long)(blk - MB3) * 2048 + tid * 8;
        *(bs8*)(hg_bf + i) = ld8cvt(h_g + i);
    } else if (blk < MB5) {
        long i = (long)(blk - MB4) * 2048 + tid * 8;
        *(bs8*)(emo_bf + i) = ld8cvt(emotion0 + i);
    } else {
        int b = blk - MB5;
        __shared__ int sid;
        if (tid == 0) {
            int best = 0; float bv = mask[b * PP];
            for (int p = 1; p < PP; ++p) { float v = mask[b * PP + p]; if (v > bv) { bv = v; best = p; } }
            sid = best; spk[b] = best;
        }
        __syncthreads();
        const float* src = sp0 + ((size_t)b * PP + sid) * SS;
        for (int j = tid; j < SS; j += 256) {
            float v = src[j];
            sel0[(size_t)b * SS + j] = v;
            short h = f2bf(v);
            sel0_bf[(size_t)b * SS + j] = h;
            xg[(size_t)b * 1536 + FF + j] = h;
        }
    }
}

// ---------------------------------------------------------------------------
// Batched bf16 MFMA GEMM (unchanged from round 6).
// ---------------------------------------------------------------------------
struct GDesc {
    const short *A, *A2, *W, *Wl;
    float* C;
    int lda, lda2, kb, ldw, woff, ldc, K, nbn, flags;
};
struct GBatch {
    GDesc d[6];
    int start[7];
    int ng;
};

__global__ __launch_bounds__(256) void k_bgemm(GBatch gb) {
    __shared__ __align__(16) short Ash[64 * 64], Bsh[64 * 64];
    __shared__ __align__(16) short Asl[64 * 64], Bsl[64 * 64];

    int bid = blockIdx.x;
    int g = 0;
    while (g + 1 < gb.ng && bid >= gb.start[g + 1]) ++g;
    GDesc d = gb.d[g];
    int local = bid - gb.start[g];
    int bn = local % d.nbn, bm = local / d.nbn;
    const bool split = (d.flags & 1) != 0;

    const int tid = threadIdx.x;
    const int lane = tid & 63, wid = tid >> 6;
    const int wr = wid >> 1, wc = wid & 1;
    const int r0 = tid >> 3, c0 = tid & 7;
    const int r1 = r0 + 32;
    const int la = lane & 15, lk = lane >> 4;
    const int sw = la & 7;

    f32x4 acc[2][2] = {};

    for (int k0 = 0; k0 < d.K; k0 += 64) {
        bs8 ah0, ah1, bh0, bh1, al0, al1, bl0, bl1;
        if (split) {
            size_t oa0 = (size_t)(bm * 64 + r0) * d.lda + k0 + c0 * 8;
            size_t oa1 = (size_t)(bm * 64 + r1) * d.lda + k0 + c0 * 8;
            size_t ow0 = (size_t)(bn * 64 + r0) * d.ldw + d.woff + k0 + c0 * 8;
            size_t ow1 = (size_t)(bn * 64 + r1) * d.ldw + d.woff + k0 + c0 * 8;
            ah0 = *(const bs8*)(d.A + oa0);  ah1 = *(const bs8*)(d.A + oa1);
            al0 = *(const bs8*)(d.A2 + oa0); al1 = *(const bs8*)(d.A2 + oa1);
            bh0 = *(const bs8*)(d.W + ow0);  bh1 = *(const bs8*)(d.W + ow1);
            bl0 = *(const bs8*)(d.Wl + ow0); bl1 = *(const bs8*)(d.Wl + ow1);
        } else {
            const short* Ab; int alda;
            if (k0 < d.kb) { Ab = d.A + k0; alda = d.lda; }
            else           { Ab = d.A2 + (k0 - d.kb); alda = d.lda2; }
            ah0 = *(const bs8*)(Ab + (size_t)(bm * 64 + r0) * alda + c0 * 8);
            ah1 = *(const bs8*)(Ab + (size_t)(bm * 64 + r1) * alda + c0 * 8);
            bh0 = *(const bs8*)(d.W + (size_t)(bn * 64 + r0) * d.ldw + d.woff + k0 + c0 * 8);
            bh1 = *(const bs8*)(d.W + (size_t)(bn * 64 + r1) * d.ldw + d.woff + k0 + c0 * 8);
        }
        __syncthreads();
        *(bs8*)(Ash + r0 * 64 + ((c0 ^ (r0 & 7)) * 8)) = ah0;
        *(bs8*)(Ash + r1 * 64 + ((c0 ^ (r1 & 7)) * 8)) = ah1;
        *(bs8*)(Bsh + r0 * 64 + ((c0 ^ (r0 & 7)) * 8)) = bh0;
        *(bs8*)(Bsh + r1 * 64 + ((c0 ^ (r1 & 7)) * 8)) = bh1;
        if (split) {
            *(bs8*)(Asl + r0 * 64 + ((c0 ^ (r0 & 7)) * 8)) = al0;
            *(bs8*)(Asl + r1 * 64 + ((c0 ^ (r1 & 7)) * 8)) = al1;
            *(bs8*)(Bsl + r0 * 64 + ((c0 ^ (r0 & 7)) * 8)) = bl0;
            *(bs8*)(Bsl + r1 * 64 + ((c0 ^ (r1 & 7)) * 8)) = bl1;
        }
        __syncthreads();
#pragma unroll
        for (int kk = 0; kk < 2; ++kk) {
            int slot = kk * 4 + lk;
            int off = (slot ^ sw) * 8;
            bs8 a0 = *(const bs8*)(Ash + (wr * 32 + la) * 64      + off);
            bs8 a1 = *(const bs8*)(Ash + (wr * 32 + 16 + la) * 64 + off);
            bs8 b0 = *(const bs8*)(Bsh + (wc * 32 + la) * 64      + off);
            bs8 b1 = *(const bs8*)(Bsh + (wc * 32 + 16 + la) * 64 + off);
            acc[0][0] = __builtin_amdgcn_mfma_f32_16x16x32_bf16(a0, b0, acc[0][0], 0, 0, 0);
            acc[0][1] = __builtin_amdgcn_mfma_f32_16x16x32_bf16(a0, b1, acc[0][1], 0, 0, 0);
            acc[1][0] = __builtin_amdgcn_mfma_f32_16x16x32_bf16(a1, b0, acc[1][0], 0, 0, 0);
            acc[1][1] = __builtin_amdgcn_mfma_f32_16x16x32_bf16(a1, b1, acc[1][1], 0, 0, 0);
            if (split) {
                bs8 xl0 = *(const bs8*)(Asl + (wr * 32 + la) * 64      + off);
                bs8 xl1 = *(const bs8*)(Asl + (wr * 32 + 16 + la) * 64 + off);
                bs8 yl0 = *(const bs8*)(Bsl + (wc * 32 + la) * 64      + off);
                bs8 yl1 = *(const bs8*)(Bsl + (wc * 32 + 16 + la) * 64 + off);
                acc[0][0] = __builtin_amdgcn_mfma_f32_16x16x32_bf16(a0, yl0, acc[0][0], 0, 0, 0);
                acc[0][0] = __builtin_amdgcn_mfma_f32_16x16x32_bf16(xl0, b0, acc[0][0], 0, 0, 0);
                acc[0][1] = __builtin_amdgcn_mfma_f32_16x16x32_bf16(a0, yl1, acc[0][1], 0, 0, 0);
                acc[0][1] = __builtin_amdgcn_mfma_f32_16x16x32_bf16(xl0, b1, acc[0][1], 0, 0, 0);
                acc[1][0] = __builtin_amdgcn_mfma_f32_16x16x32_bf16(a1, yl0, acc[1][0], 0, 0, 0);
                acc[1][0] = __builtin_amdgcn_mfma_f32_16x16x32_bf16(xl1, b0, acc[1][0], 0, 0, 0);
                acc[1][1] = __builtin_amdgcn_mfma_f32_16x16x32_bf16(a1, yl1, acc[1][1], 0, 0, 0);
                acc[1][1] = __builtin_amdgcn_mfma_f32_16x16x32_bf16(xl1, b1, acc[1][1], 0, 0, 0);
            }
        }
    }

    const int rowb = (lane >> 4) * 4, coln = lane & 15;
#pragma unroll
    for (int i = 0; i < 2; ++i)
#pragma unroll
    for (int j = 0; j < 2; ++j)
#pragma unroll
    for (int r = 0; r < 4; ++r) {
        int row = bm * 64 + wr * 32 + i * 16 + rowb + r;
        int col = bn * 64 + wc * 32 + j * 16 + coln;
        d.C[(size_t)row * d.ldc + col] = acc[i][j][r];
    }
}

// ---------------------------------------------------------------------------
// Split-T flash attention (unchanged).
// ---------------------------------------------------------------------------
__global__ __launch_bounds__(256) void k_attnp(const float* __restrict__ x_,
                                               const float* __restrict__ gh,
                                               float* __restrict__ ctxp,
                                               float2* __restrict__ msb) {
    int blk = blockIdx.x;
    int b = blk & (BB - 1), ch = blk >> 8;
    int tid = threadIdx.x, w = tid >> 6, lane = tid & 63;
    __shared__ float wm[4], ws[4];
    __shared__ float part[4][GG];

    const float* xb = x_ + (size_t)b * GG + lane * 8;
    float4 xa = *(const float4*)xb;
    float4 xc = *(const float4*)(xb + 4);

    float m = -INFINITY, s = 0.f;
    float acc[8] = {};
    int t0 = ch * 32 + w * 8;
#pragma unroll
    for (int it = 0; it < 8; ++it) {
        int t = t0 + it;
        const float* row = gh + ((size_t)t * BB + b) * GG + lane * 8;
        float4 v1 = *(const float4*)row;
        float4 v2 = *(const float4*)(row + 4);
        float p = v1.x*xa.x + v1.y*xa.y + v1.z*xa.z + v1.w*xa.w
                + v2.x*xc.x + v2.y*xc.y + v2.z*xc.z + v2.w*xc.w;
#pragma unroll
        for (int off = 32; off; off >>= 1) p += __shfl_xor(p, off);
        float nm = fmaxf(m, p);
        float scale = expf(m - nm);
        float e = expf(p - nm);
        s = s * scale + e;
        acc[0] = acc[0]*scale + e*v1.x; acc[1] = acc[1]*scale + e*v1.y;
        acc[2] = acc[2]*scale + e*v1.z; acc[3] = acc[3]*scale + e*v1.w;
        acc[4] = acc[4]*scale + e*v2.x; acc[5] = acc[5]*scale + e*v2.y;
        acc[6] = acc[6]*scale + e*v2.z; acc[7] = acc[7]*scale + e*v2.w;
        m = nm;
    }
    if (lane == 0) { wm[w] = m; ws[w] = s; }
    *(float4*)&part[w][lane * 8]     = make_float4(acc[0], acc[1], acc[2], acc[3]);
    *(float4*)&part[w][lane * 8 + 4] = make_float4(acc[4], acc[5], acc[6], acc[7]);
    __syncthreads();

    float M = fmaxf(fmaxf(wm[0], wm[1]), fmaxf(wm[2], wm[3]));
    float f0 = expf(wm[0] - M), f1 = expf(wm[1] - M);
    float f2 = expf(wm[2] - M), f3 = expf(wm[3] - M);
    if (tid == 0) {
        float S = ws[0]*f0 + ws[1]*f1 + ws[2]*f2 + ws[3]*f3;
        msb[blk] = make_float2(M, S);
    }
    for (int j = tid; j < GG; j += 256) {
        float r = part[0][j]*f0 + part[1][j]*f1 + part[2][j]*f2 + part[3][j]*f3;
        ctxp[(size_t)blk * GG + j] = r;
    }
}

// ---------------------------------------------------------------------------
// k_tail1: blocks [0,32): in-block ctx merge + ctx@Wp_ih[:,F:] 3-gate GEMM +
//          parties-GRU epilogue (par_bf + speaker scatter).
//          blocks [32,544): global GRU elementwise.
// ---------------------------------------------------------------------------
#define T1G 32
__global__ __launch_bounds__(256) void k_tail1(
        const float* __restrict__ ctxp, const float2* __restrict__ msb,
        const short* __restrict__ Wp_ih_bf,
        const float* __restrict__ gi_p, const float* __restrict__ gh_p,
        const float* __restrict__ bp_ih, const float* __restrict__ bp_hh,
        const float* __restrict__ sel0, const int* __restrict__ spk,
        short* __restrict__ par_bf, float* __restrict__ speaker_out,
        const float* __restrict__ gi_g, const float* __restrict__ gh_g,
        const float* __restrict__ bg_ih, const float* __restrict__ bg_hh,
        const float* __restrict__ hg, float* __restrict__ global_out) {
    int bid = blockIdx.x, tid = threadIdx.x;
    if (bid >= T1G) {
        int idx = (bid - T1G) * 256 + tid;          // over B*G
        int b = idx / GG, j = idx - b * GG;
        const float* gib = gi_g + (size_t)b * 3 * GG;
        const float* ghb = gh_g + (size_t)b * 3 * GG;
        float r = sigmoidf_(gib[j] + bg_ih[j] + ghb[j] + bg_hh[j]);
        float z = sigmoidf_(gib[GG + j] + bg_ih[GG + j] + ghb[GG + j] + bg_hh[GG + j]);
        float n = tanhf(gib[2*GG + j] + bg_ih[2*GG + j] + r * (ghb[2*GG + j] + bg_hh[2*GG + j]));
        global_out[idx] = (1.0f - z) * n + z * hg[idx];
        return;
    }

    __shared__ __align__(16) short Actx[64 * 512];
    __shared__ __align__(16) short Bs[3][64 * 64];
    __shared__ float f_lds[64][8];

    int bm = bid >> 3, bn = bid & 7;
    int brow = bm * 64;

    // per-row flash merge factors
    if (tid < 64) {
        int b = brow + tid;
        float mv[8], sv[8];
        float M = -INFINITY;
#pragma unroll
        for (int c = 0; c < 8; ++c) {
            float2 t = msb[c * BB + b];
            mv[c] = t.x; sv[c] = t.y;
            M = fmaxf(M, t.x);
        }
        float fv[8], S = 0.f;
#pragma unroll
        for (int c = 0; c < 8; ++c) { fv[c] = expf(mv[c] - M); S += sv[c] * fv[c]; }
        float inv = 1.0f / S;
#pragma unroll
        for (int c = 0; c < 8; ++c) f_lds[tid][c] = fv[c] * inv;
    }
    __syncthreads();

    // build merged-ctx A tile: 64 rows x 512 cols, bf16, swizzled per 64-col chunk
    for (int gidx = tid; gidx < 64 * 64; gidx += 256) {
        int row = gidx >> 6, gr = gidx & 63;        // gr = 8-col granule idx
        int c64 = gr >> 3, slot = gr & 7;
        int k = gr * 8;
        int b = brow + row;
        float a0 = 0.f, a1 = 0.f, a2 = 0.f, a3 = 0.f, a4 = 0.f, a5 = 0.f, a6 = 0.f, a7 = 0.f;
#pragma unroll
        for (int c = 0; c < 8; ++c) {
            float fcb = f_lds[row][c];
            const float* p = ctxp + ((size_t)(c * BB + b)) * GG + k;
            float4 v1 = *(const float4*)p;
            float4 v2 = *(const float4*)(p + 4);
            a0 += fcb * v1.x; a1 += fcb * v1.y; a2 += fcb * v1.z; a3 += fcb * v1.w;
            a4 += fcb * v2.x; a5 += fcb * v2.y; a6 += fcb * v2.z; a7 += fcb * v2.w;
        }
        BPack u;
        u.h[0] = __float22bfloat162_rn({a0, a1});
        u.h[1] = __float22bfloat162_rn({a2, a3});
        u.h[2] = __float22bfloat162_rn({a4, a5});
        u.h[3] = __float22bfloat162_rn({a6, a7});
        *(bs8*)(Actx + row * 512 + c64 * 64 + ((slot ^ (row & 7)) * 8)) = u.s;
    }
    __syncthreads();

    const int lane = tid & 63, wid = tid >> 6;
    const int wr = wid >> 1, wc = wid & 1;
    const int r0 = tid >> 3, c0 = tid & 7;
    const int r1 = r0 + 32;
    const int la = lane & 15, lk = lane >> 4;
    const int sw = la & 7;

    f32x4 acc[3][2][2] = {};

    for (int k0 = 0; k0 < 512; k0 += 64) {
        bs8 b0g[3], b1g[3];
#pragma unroll
        for (int g = 0; g < 3; ++g) {
            b0g[g] = *(const bs8*)(Wp_ih_bf + (size_t)(g * 512 + bn * 64 + r0) * 1536 + FF + k0 + c0 * 8);
            b1g[g] = *(const bs8*)(Wp_ih_bf + (size_t)(g * 512 + bn * 64 + r1) * 1536 + FF + k0 + c0 * 8);
        }
        __syncthreads();
#pragma unroll
        for (int g = 0; g < 3; ++g) {
            *(bs8*)(Bs[g] + r0 * 64 + ((c0 ^ (r0 & 7)) * 8)) = b0g[g];
            *(bs8*)(Bs[g] + r1 * 64 + ((c0 ^ (r1 & 7)) * 8)) = b1g[g];
        }
        __syncthreads();
#pragma unroll
        for (int kk = 0; kk < 2; ++kk) {
            int slot = kk * 4 + lk;
            int off = (slot ^ sw) * 8;
            bs8 a0 = *(const bs8*)(Actx + (wr * 32 + la) * 512      + k0 + off);
            bs8 a1 = *(const bs8*)(Actx + (wr * 32 + 16 + la) * 512 + k0 + off);
#pragma unroll
            for (int g = 0; g < 3; ++g) {
                bs8 bb0 = *(const bs8*)(Bs[g] + (wc * 32 + la) * 64      + off);
                bs8 bb1 = *(const bs8*)(Bs[g] + (wc * 32 + 16 + la) * 64 + off);
                acc[g][0][0] = __builtin_amdgcn_mfma_f32_16x16x32_bf16(a0, bb0, acc[g][0][0], 0, 0, 0);
                acc[g][0][1] = __builtin_amdgcn_mfma_f32_16x16x32_bf16(a0, bb1, acc[g][0][1], 0, 0, 0);
                acc[g][1][0] = __builtin_amdgcn_mfma_f32_16x16x32_bf16(a1, bb0, acc[g][1][0], 0, 0, 0);
                acc[g][1][1] = __builtin_amdgcn_mfma_f32_16x16x32_bf16(a1, bb1, acc[g][1][1], 0, 0, 0);
            }
        }
    }

    const int rowb = (lane >> 4) * 4, coln = lane & 15;
#pragma unroll
    for (int i = 0; i < 2; ++i)
#pragma unroll
    for (int r = 0; r < 4; ++r) {
        int row = brow + wr * 32 + i * 16 + rowb + r;
        int sp = spk[row];
#pragma unroll
        for (int j = 0; j < 2; ++j) {
            int col = bn * 64 + wc * 32 + j * 16 + coln;   // 0..511
            const float* gib = gi_p + (size_t)row * 1536;
            const float* ghb = gh_p + (size_t)row * 1536;
            float gr_ = sigmoidf_(acc[0][i][j][r] + gib[col] + bp_ih[col] + ghb[col] + bp_hh[col]);
            float gz  = sigmoidf_(acc[1][i][j][r] + gib[512 + col] + bp_ih[512 + col] + ghb[512 + col] + bp_hh[512 + col]);
            float gn  = tanhf(acc[2][i][j][r] + gib[1024 + col] + bp_ih[1024 + col] + gr_ * (ghb[1024 + col] + bp_hh[1024 + col]));
            float o = (1.0f - gz) * gn + gz * sel0[(size_t)row * SS + col];
            par_bf[(size_t)row * SS + col] = f2bf(o);
            speaker_out[((size_t)row * PP + sp) * SS + col] = o;
        }
    }
}

// ---------------------------------------------------------------------------
// k_tail2: blocks [0,16): parties@We_ih 3-gate GEMM + emotion-GRU epilogue.
//          blocks [16,1040): speaker0 copy with skip of selected rows.
// ---------------------------------------------------------------------------
#define T2G 16
__global__ __launch_bounds__(256) void k_tail2(
        const short* __restrict__ par_bf, const short* __restrict__ We_ih_bf,
        const float* __restrict__ gh_e,
        const float* __restrict__ be_ih, const float* __restrict__ be_hh,
        const float* __restrict__ emotion0, float* __restrict__ emotion_out,
        const float* __restrict__ sp0, const int* __restrict__ spk,
        float* __restrict__ speaker_out) {
    int bid = blockIdx.x, tid = threadIdx.x;
    if (bid >= T2G) {
        size_t i = ((size_t)(bid - T2G) * 256 + tid) * 4;   // over B*P*S
        int b = (int)(i >> 12);
        int p = (int)(i >> 9) & 7;
        if (p != spk[b]) *(float4*)(speaker_out + i) = *(const float4*)(sp0 + i);
        return;
    }

    __shared__ __align__(16) short Ash[64 * 64];
    __shared__ __align__(16) short Bs[3][64 * 64];

    int bm = bid >> 2, bn = bid & 3;
    int brow = bm * 64;

    const int lane = tid & 63, wid = tid >> 6;
    const int wr = wid >> 1, wc = wid & 1;
    const int r0 = tid >> 3, c0 = tid & 7;
    const int r1 = r0 + 32;
    const int la = lane & 15, lk = lane >> 4;
    const int sw = la & 7;

    f32x4 acc[3][2][2] = {};

    for (int k0 = 0; k0 < 512; k0 += 64) {
        bs8 ah0 = *(const bs8*)(par_bf + (size_t)(brow + r0) * 512 + k0 + c0 * 8);
        bs8 ah1 = *(const bs8*)(par_bf + (size_t)(brow + r1) * 512 + k0 + c0 * 8);
        bs8 b0g[3], b1g[3];
#pragma unroll
        for (int g = 0; g < 3; ++g) {
            b0g[g] = *(const bs8*)(We_ih_bf + (size_t)(g * 256 + bn * 64 + r0) * 512 + k0 + c0 * 8);
            b1g[g] = *(const bs8*)(We_ih_bf + (size_t)(g * 256 + bn * 64 + r1) * 512 + k0 + c0 * 8);
        }
        __syncthreads();
        *(bs8*)(Ash + r0 * 64 + ((c0 ^ (r0 & 7)) * 8)) = ah0;
        *(bs8*)(Ash + r1 * 64 + ((c0 ^ (r1 & 7)) * 8)) = ah1;
#pragma unroll
        for (int g = 0; g < 3; ++g) {
            *(bs8*)(Bs[g] + r0 * 64 + ((c0 ^ (r0 & 7)) * 8)) = b0g[g];
            *(bs8*)(Bs[g] + r1 * 64 + ((c0 ^ (r1 & 7)) * 8)) = b1g[g];
        }
        __syncthreads();
#pragma unroll
        for (int kk = 0; kk < 2; ++kk) {
            int slot = kk * 4 + lk;
            int off = (slot ^ sw) * 8;
            bs8 a0 = *(const bs8*)(Ash + (wr * 32 + la) * 64      + off);
            bs8 a1 = *(const bs8*)(Ash + (wr * 32 + 16 + la) * 64 + off);
#pragma unroll
            for (int g = 0; g < 3; ++g) {
                bs8 bb0 = *(const bs8*)(Bs[g] + (wc * 32 + la) * 64      + off);
                bs8 bb1 = *(const bs8*)(Bs[g] + (wc * 32 + 16 + la) * 64 + off);
                acc[g][0][0] = __builtin_amdgcn_mfma_f32_16x16x32_bf16(a0, bb0, acc[g][0][0], 0, 0, 0);
                acc[g][0][1] = __builtin_amdgcn_mfma_f32_16x16x32_bf16(a0, bb1, acc[g][0][1], 0, 0, 0);
                acc[g][1][0] = __builtin_amdgcn_mfma_f32_16x16x32_bf16(a1, bb0, acc[g][1][0], 0, 0, 0);
                acc[g][1][1] = __builtin_amdgcn_mfma_f32_16x16x32_bf16(a1, bb1, acc[g][1][1], 0, 0, 0);
            }
        }
    }

    const int rowb = (lane >> 4) * 4, coln = lane & 15;
#pragma unroll
    for (int i = 0; i < 2; ++i)
#pragma unroll
    for (int r = 0; r < 4; ++r) {
        int row = brow + wr * 32 + i * 16 + rowb + r;
#pragma unroll
        for (int j = 0; j < 2; ++j) {
            int col = bn * 64 + wc * 32 + j * 16 + coln;   // 0..255
            const float* ghb = gh_e + (size_t)row * 768;
            float gr_ = sigmoidf_(acc[0][i][j][r] + be_ih[col] + ghb[col] + be_hh[col]);
            float gz  = sigmoidf_(acc[1][i][j][r] + be_ih[256 + col] + ghb[256 + col] + be_hh[256 + col]);
            float gn  = tanhf(acc[2][i][j][r] + be_ih[512 + col] + gr_ * (ghb[512 + col] + be_hh[512 + col]));
            emotion_out[(size_t)row * EE + col] = (1.0f - gz) * gn + gz * emotion0[(size_t)row * EE + col];
        }
    }
}

// ---------------------------------------------------------------------------
extern "C" void kernel_launch(void* const* d_in, const int* in_sizes, int n_in,
                              void* d_out, int out_size, void* d_ws, size_t ws_size,
                              hipStream_t stream) {
    const float* feature_ = (const float*)d_in[0];
    const float* mask     = (const float*)d_in[1];
    const float* ghist    = (const float*)d_in[2];
    const float* speaker0 = (const float*)d_in[3];
    const float* emotion0 = (const float*)d_in[4];
    const float* Wg_ih    = (const float*)d_in[5];
    const float* Wg_hh    = (const float*)d_in[6];
    const float* bg_ih    = (const float*)d_in[7];
    const float* bg_hh    = (const float*)d_in[8];
    const float* Wp_ih    = (const float*)d_in[9];
    const float* Wp_hh    = (const float*)d_in[10];
    const float* bp_ih    = (const float*)d_in[11];
    const float* bp_hh    = (const float*)d_in[12];
    const float* We_ih    = (const float*)d_in[13];
    const float* We_hh    = (const float*)d_in[14];
    const float* be_ih    = (const float*)d_in[15];
    const float* be_hh    = (const float*)d_in[16];
    const float* attn_W   = (const float*)d_in[17];

    float* out = (float*)d_out;
    float* emotion_out = out;
    float* global_out  = out + (size_t)BB * EE;
    float* speaker_out = global_out + (size_t)BB * GG;

    char* cur = (char*)d_ws;
    short* Wbf     = (short*)cur; cur += (size_t)WTOT * 2;
    short* awhi    = (short*)cur; cur += (size_t)GG * FF * 2;
    short* awlo    = (short*)cur; cur += (size_t)GG * FF * 2;
    short* xg      = (short*)cur; cur += (size_t)BB * 1536 * 2;
    short* fhi     = (short*)cur; cur += (size_t)BB * FF * 2;
    short* flo     = (short*)cur; cur += (size_t)BB * FF * 2;
    short* hg_bf   = (short*)cur; cur += (size_t)BB * GG * 2;
    short* emo_bf  = (short*)cur; cur += (size_t)BB * EE * 2;
    short* sel0_bf = (short*)cur; cur += (size_t)BB * SS * 2;
    short* par_bf  = (short*)cur; cur += (size_t)BB * SS * 2;

    float* sel0    = (float*)cur; cur += (size_t)BB * SS * 4;
    float* x_      = (float*)cur; cur += (size_t)BB * GG * 4;
    float* ctxp    = (float*)cur; cur += (size_t)2048 * GG * 4;
    float2* msb    = (float2*)cur; cur += (size_t)2048 * 8;
    float* gi_g    = (float*)cur; cur += (size_t)BB * 3 * GG * 4;
    float* gh_g    = (float*)cur; cur += (size_t)BB * 3 * GG * 4;
    float* gi_p    = (float*)cur; cur += (size_t)BB * 3 * SS * 4;
    float* gh_p    = (float*)cur; cur += (size_t)BB * 3 * SS * 4;
    float* gh_e    = (float*)cur; cur += (size_t)BB * 3 * EE * 4;
    int*   spk     = (int*)cur;   cur += 256 * 4;

    const float* h_g = ghist + (size_t)(TT - 1) * BB * GG;

    short* Wg_ih_bf = Wbf + OWG_IH;
    short* Wg_hh_bf = Wbf + OWG_HH;
    short* Wp_ih_bf = Wbf + OWP_IH;
    short* Wp_hh_bf = Wbf + OWP_HH;
    short* We_ih_bf = Wbf + OWE_IH;
    short* We_hh_bf = Wbf + OWE_HH;

    // 1) conversions + gather
    k_mega<<<MBE, 256, 0, stream>>>(Wg_ih, Wg_hh, Wp_ih, Wp_hh, We_ih, We_hh,
                                    attn_W, feature_, h_g, emotion0, mask, speaker0,
                                    Wbf, awhi, awlo, xg, fhi, flo, hg_bf, emo_bf,
                                    sel0_bf, sel0, spk);

    // 2) batchA: x_(split) + all attention-independent GEMMs
    GBatch gbA;
    gbA.d[0] = { fhi, flo, awhi, awlo, x_, FF, FF, FF, FF, 0, GG, FF, 8, 1 };
    gbA.d[1] = { xg, xg, Wg_ih_bf, nullptr, gi_g, 1536, 1536, 1536, 1536, 0, 3*GG, 1536, 24, 0 };
    gbA.d[2] = { hg_bf, hg_bf, Wg_hh_bf, nullptr, gh_g, GG, GG, GG, GG, 0, 3*GG, GG, 24, 0 };
    gbA.d[3] = { sel0_bf, sel0_bf, Wp_hh_bf, nullptr, gh_p, SS, SS, SS, SS, 0, 3*SS, SS, 24, 0 };
    gbA.d[4] = { emo_bf, emo_bf, We_hh_bf, nullptr, gh_e, EE, EE, EE, EE, 0, 3*EE, EE, 12, 0 };
    gbA.d[5] = { xg, xg, Wp_ih_bf, nullptr, gi_p, 1536, 1536, 1536, 1536, 0, 3*SS, FF, 24, 0 };
    gbA.start[0] = 0;   gbA.start[1] = 32;  gbA.start[2] = 128; gbA.start[3] = 224;
    gbA.start[4] = 320; gbA.start[5] = 368; gbA.start[6] = 464;
    gbA.ng = 6;
    k_bgemm<<<464, 256, 0, stream>>>(gbA);

    // 3) flash attention partials (single history read)
    k_attnp<<<2048, 256, 0, stream>>>(x_, ghist, ctxp, msb);

    // 4) tail1: ctx merge + parties GEMM/GRU + scatter; global GRU as fill
    k_tail1<<<T1G + (BB * GG) / 256, 256, 0, stream>>>(
        ctxp, msb, Wp_ih_bf, gi_p, gh_p, bp_ih, bp_hh, sel0, spk,
        par_bf, speaker_out,
        gi_g, gh_g, bg_ih, bg_hh, h_g, global_out);

    // 5) tail2: emotion GEMM/GRU; speaker skip-copy as fill
    k_tail2<<<T2G + (BB * PP * SS) / 4 / 256, 256, 0, stream>>>(
        par_bf, We_ih_bf, gh_e, be_ih, be_hh, emotion0, emotion_out,
        speaker0, spk, speaker_out);
}